// Round 6
// baseline (963.114 us; speedup 1.0000x reference)
//
#include <hip/hip_runtime.h>
#include <math.h>

#define PP 128
#define DD 128
#define RR 16384
#define EE 131072
#define TT 1024
#define FF 513
#define FP 520          /* padded f count */
#define FP2 1040        /* floats per row (interleaved complex) */
#define KSTRIDE 132     /* LDS row stride for K tile: 16B-aligned, conflict-free */
#define NRB 4096        /* segsum row-blocks (4 rows each) */
#define PSTRIDE 528     /* part row stride in float2 */

#define TAU_SCALE 46.64723032069971    /* SR / C_SOUND */
#define KDECAY   -0.0211392282f        /* LOG_GAMMA/C - AIR */
#define LOG_GAMMA -6.907755278982137f
#define TWO_PI    6.283185307179586

__device__ __forceinline__ void pf_sincos(float tau, int f, float* s, float* c) {
    // phase = exp(-2*pi*i * tau * f / T); reduce in double, eval in float
    double rev = (double)tau * (double)f * (1.0 / 1024.0);
    rev -= floor(rev);
    float ang = (float)(-TWO_PI * rev);
    __sincosf(ang, s, c);
}

// ---- per-row precompute: amp_src, tau_src, amp_rec, tau_rec, dec_prop, tau_prop
__global__ void k_per_row(const float* __restrict__ rpos,
                          const float* __restrict__ spos,
                          const float* __restrict__ cpos,
                          const float* __restrict__ avg_dist,
                          float* __restrict__ per_row) {
    int r = blockIdx.x * blockDim.x + threadIdx.x;
    if (r >= RR) return;
    float x = rpos[3*r], y = rpos[3*r+1], z = rpos[3*r+2];

    float dx = x - spos[0], dy = y - spos[1], dz = z - spos[2];
    float ds = sqrtf(dx*dx + dy*dy + dz*dz);
    per_row[0*RR + r] = (1.0f/(ds*ds + 0.001f)) * expf(KDECAY * ds);
    per_row[1*RR + r] = ds * (float)TAU_SCALE;

    dx = x - cpos[0]; dy = y - cpos[1]; dz = z - cpos[2];
    float dr = sqrtf(dx*dx + dy*dy + dz*dz);
    per_row[2*RR + r] = (1.0f/(dr*dr + 0.001f)) * expf(KDECAY * dr);
    per_row[3*RR + r] = dr * (float)TAU_SCALE;

    float da = avg_dist[r];
    per_row[4*RR + r] = expf(KDECAY * da);
    per_row[5*RR + r] = da * (float)TAU_SCALE;
}

// ---- Kt[p][e][d] = refl*sc*basis0[d][e] + refl*(1-sc)*basis1[d][e]  (transposed)
__global__ void k_build_Kt(const float* __restrict__ absorption,
                           const float* __restrict__ scattering,
                           const int* __restrict__ object_ids,
                           const float* __restrict__ basis,
                           float* __restrict__ Kt) {
    int idx = blockIdx.x * 256 + threadIdx.x;   // p*16384 + e*128 + d
    int p = idx >> 14;
    int e = (idx >> 7) & 127;
    int d = idx & 127;
    int obj = object_ids[p];
    float refl = 1.0f - absorption[obj];
    float sc   = scattering[obj];
    int de = d * 128 + e;
    Kt[idx] = refl*sc*basis[de] + refl*(1.0f - sc)*basis[16384 + de];
}

// ---- CSR build
__global__ void k_count(const int* __restrict__ gk_row, int* __restrict__ counts) {
    int e = blockIdx.x * 256 + threadIdx.x;
    atomicAdd(&counts[gk_row[e]], 1);
}

__global__ __launch_bounds__(1024) void k_scan(const int* __restrict__ counts,
                                               int* __restrict__ row_start,
                                               int* __restrict__ cursor) {
    __shared__ int sh[1024];
    int tid = threadIdx.x;
    int base = tid * 16;
    int local[16];
    int sum = 0;
    #pragma unroll
    for (int j = 0; j < 16; j++) { local[j] = sum; sum += counts[base + j]; }
    sh[tid] = sum;
    __syncthreads();
    for (int off = 1; off < 1024; off <<= 1) {
        int v = (tid >= off) ? sh[tid - off] : 0;
        __syncthreads();
        sh[tid] += v;
        __syncthreads();
    }
    int chunk_excl = sh[tid] - sum;   // exclusive prefix of this 16-chunk
    #pragma unroll
    for (int j = 0; j < 16; j++) {
        int v = chunk_excl + local[j];
        row_start[base + j] = v;
        cursor[base + j] = v;
    }
    if (tid == 1023) row_start[RR] = chunk_excl + sum;
}

// scatter packing {col, val} per edge -> one b64 load in segsum
__global__ void k_scatter(const int* __restrict__ gk_row,
                          const float* __restrict__ gk_val,
                          const int* __restrict__ gk_col,
                          int* __restrict__ cursor,
                          int2* __restrict__ edge) {
    int e = blockIdx.x * 256 + threadIdx.x;
    int pos = atomicAdd(&cursor[gk_row[e]], 1);
    edge[pos] = make_int2(gk_col[e], __float_as_int(gk_val[e]));
}

// ---- init: cur[r][f] = amp_src*phase(tau_src); fused rad receiver-echo
__global__ __launch_bounds__(256) void k_init(const float* __restrict__ per_row,
                                              float* __restrict__ cur,
                                              float* __restrict__ echo) {
    int fl = threadIdx.x & 63, rg = threadIdx.x >> 6;
    int f = blockIdx.x * 64 + fl;               // < 576
    float ar = 0.f, ai = 0.f;
    int r0 = blockIdx.y * 128;
    if (f < FP) {
        for (int k = rg; k < 128; k += 4) {
            int r = r0 + k;
            float amp = per_row[r], tau = per_row[RR + r];
            float s, c; pf_sincos(tau, f, &s, &c);
            float re = amp * c, im = amp * s;
            *(float2*)(cur + (size_t)r * FP2 + f * 2) = make_float2(re, im);
            if (f < FF) {
                float w = per_row[2*RR + r], taur = per_row[3*RR + r];
                float s2, c2; pf_sincos(taur, f, &s2, &c2);
                ar = fmaf(w, c2*re - s2*im, ar);
                ai = fmaf(w, c2*im + s2*re, ai);
            }
        }
    }
    __shared__ float sh[4][64][2];
    sh[rg][fl][0] = ar; sh[rg][fl][1] = ai;
    __syncthreads();
    if (rg == 0 && f < FF) {
        float sx = sh[0][fl][0]+sh[1][fl][0]+sh[2][fl][0]+sh[3][fl][0];
        float sy = sh[0][fl][1]+sh[1][fl][1]+sh[2][fl][1]+sh[3][fl][1];
        atomicAdd(&echo[2*f],   sx);
        atomicAdd(&echo[2*f+1], sy);
    }
}

// ---- matmul + prop: out[p*128+d][f] = prop * sum_e Kt[p][e][d] * in[p*128+e][f]
// 1-D grid 2176 = 128 p x 17 ftiles(32 f), XCD-swizzled. 256 thr = 16 dg(8 d)
// x 16 fp(2 complex f). K staged in TWO 64-e chunks (LDS 33.8 KB -> 4 blk/CU).
// unroll 8: 8 global dwordx4 in flight per wave to cover VMEM latency.
__global__ __launch_bounds__(256) void k_matmul(const float* __restrict__ Kt,
                                                const float* __restrict__ in,
                                                const float* __restrict__ per_row,
                                                float* __restrict__ out) {
    __shared__ float Klds[64 * KSTRIDE];   // [e-chunk][d]
    int b = blockIdx.x;
    int xcd = b & 7;
    int g = b >> 3;                 // 272 groups
    int p = (g / 17) * 8 + xcd;
    int ftile = g % 17;
    int tid = threadIdx.x;

    int fp = tid & 15;              // f-pair
    int dg = tid >> 4;              // 8-d group
    int f = (ftile << 5) + (fp << 1);
    const float* vbase = in + (size_t)(p << 7) * FP2 + f * 2;
    float acc[8][4];
    #pragma unroll
    for (int j = 0; j < 8; j++) { acc[j][0]=0.f; acc[j][1]=0.f; acc[j][2]=0.f; acc[j][3]=0.f; }
    const float* kbase = Klds + (dg << 3);

    for (int chunk = 0; chunk < 2; chunk++) {
        const float* Kp = Kt + (p << 14) + (chunk << 13);
        if (chunk) __syncthreads();           // protect readers of prev chunk
        for (int i = tid; i < 8192; i += 256)
            Klds[(i >> 7) * KSTRIDE + (i & 127)] = Kp[i];
        __syncthreads();
        const float* vb = vbase + (size_t)(chunk << 6) * FP2;
        #pragma unroll 8
        for (int ee = 0; ee < 64; ee++) {
            float4 v = *(const float4*)(vb + (size_t)ee * FP2);
            const float* kr = kbase + ee * KSTRIDE;
            #pragma unroll
            for (int j = 0; j < 8; j++) {
                float kv = kr[j];
                acc[j][0] = fmaf(kv, v.x, acc[j][0]);
                acc[j][1] = fmaf(kv, v.y, acc[j][1]);
                acc[j][2] = fmaf(kv, v.z, acc[j][2]);
                acc[j][3] = fmaf(kv, v.w, acc[j][3]);
            }
        }
    }
    if (f < FP) {                   // f<=518: stores f, f+1 both valid
        int d0 = dg << 3;
        #pragma unroll
        for (int j = 0; j < 8; j++) {
            int row = (p << 7) + d0 + j;
            float dec = per_row[4*RR + row];
            float tau = per_row[5*RR + row];
            float s0,c0,s1,c1;
            pf_sincos(tau, f,   &s0, &c0);
            pf_sincos(tau, f+1, &s1, &c1);
            float4 o;
            o.x = dec*(acc[j][0]*c0 - acc[j][1]*s0);
            o.y = dec*(acc[j][1]*c0 + acc[j][0]*s0);
            o.z = dec*(acc[j][2]*c1 - acc[j][3]*s1);
            o.w = dec*(acc[j][3]*c1 + acc[j][2]*s1);
            *(float4*)(out + (size_t)row * FP2 + f * 2) = o;
        }
    }
}

// ---- segment sum + fused receiver-echo epilogue.
// 4096 blocks x 512 thr = 128 fl x 4 ry. Each lane: 4 f-slices (fl, fl+128,
// fl+256, fl+384) + tail (fl<8: 512+fl). Echo partials reduced over the 4 rows
// in LDS, accumulated (non-atomic) into part[rowblk][f]; k_fold sums at end.
__global__ __launch_bounds__(512) void k_segsum(const int* __restrict__ row_start,
                                                const int2* __restrict__ edge,
                                                const float* __restrict__ in,
                                                float* __restrict__ outp,
                                                const float* __restrict__ per_row,
                                                float2* __restrict__ part,
                                                int store_cur) {
    __shared__ float2 sh[4][128][5];
    int rb = blockIdx.x;
    int fl = threadIdx.x & 127, ry = threadIdx.x >> 7;
    int row = (rb << 2) + ry;
    int s0 = row_start[row], s1 = row_start[row + 1];
    float a0r=0.f,a0i=0.f,a1r=0.f,a1i=0.f,a2r=0.f,a2i=0.f,a3r=0.f,a3i=0.f;
    float t4r=0.f,t4i=0.f;
    bool tail = (fl < 8);
    for (int t = s0; t < s1; t++) {
        int2 ed = edge[t];
        float v = __int_as_float(ed.y);
        const float* g = in + (size_t)ed.x * FP2 + fl * 2;
        float2 g0 = *(const float2*)(g);
        float2 g1 = *(const float2*)(g + 256);
        float2 g2 = *(const float2*)(g + 512);
        float2 g3 = *(const float2*)(g + 768);
        a0r = fmaf(v, g0.x, a0r); a0i = fmaf(v, g0.y, a0i);
        a1r = fmaf(v, g1.x, a1r); a1i = fmaf(v, g1.y, a1i);
        a2r = fmaf(v, g2.x, a2r); a2i = fmaf(v, g2.y, a2i);
        a3r = fmaf(v, g3.x, a3r); a3i = fmaf(v, g3.y, a3i);
        if (tail) {
            float2 g4 = *(const float2*)(g + 1024);
            t4r = fmaf(v, g4.x, t4r); t4i = fmaf(v, g4.y, t4i);
        }
    }
    if (store_cur) {
        float* w = outp + (size_t)row * FP2 + fl * 2;
        *(float2*)(w)        = make_float2(a0r, a0i);
        *(float2*)(w + 256)  = make_float2(a1r, a1i);
        *(float2*)(w + 512)  = make_float2(a2r, a2i);
        *(float2*)(w + 768)  = make_float2(a3r, a3i);
        if (tail) *(float2*)(w + 1024) = make_float2(t4r, t4i);
    }
    // echo epilogue: contrib(f) = w_rec * phase(tau_rec, f) * value
    float wr = per_row[2*RR + row], taur = per_row[3*RR + row];
    {
        float s, c;
        pf_sincos(taur, fl, &s, &c);
        sh[ry][fl][0] = make_float2(wr*(c*a0r - s*a0i), wr*(c*a0i + s*a0r));
        pf_sincos(taur, fl + 128, &s, &c);
        sh[ry][fl][1] = make_float2(wr*(c*a1r - s*a1i), wr*(c*a1i + s*a1r));
        pf_sincos(taur, fl + 256, &s, &c);
        sh[ry][fl][2] = make_float2(wr*(c*a2r - s*a2i), wr*(c*a2i + s*a2r));
        pf_sincos(taur, fl + 384, &s, &c);
        sh[ry][fl][3] = make_float2(wr*(c*a3r - s*a3i), wr*(c*a3i + s*a3r));
        float2 c4 = make_float2(0.f, 0.f);
        if (tail && (512 + fl) < FF) {       // f=512 only
            pf_sincos(taur, 512 + fl, &s, &c);
            c4 = make_float2(wr*(c*t4r - s*t4i), wr*(c*t4i + s*t4r));
        }
        sh[ry][fl][4] = c4;
    }
    __syncthreads();
    if (ry == 0) {
        float2* pp = part + (size_t)rb * PSTRIDE;
        #pragma unroll
        for (int sidx = 0; sidx < 5; sidx++) {
            int fidx = sidx * 128 + fl;
            if (fidx < FP) {
                float2 v0 = sh[0][fl][sidx], v1 = sh[1][fl][sidx];
                float2 v2 = sh[2][fl][sidx], v3 = sh[3][fl][sidx];
                float2 acc = pp[fidx];
                acc.x += v0.x + v1.x + v2.x + v3.x;
                acc.y += v0.y + v1.y + v2.y + v3.y;
                pp[fidx] = acc;
            }
        }
    }
}

// ---- fold echo partials: echo[f] += sum_rb part[rb][f]
__global__ __launch_bounds__(256) void k_fold(const float2* __restrict__ part,
                                              float* __restrict__ echo) {
    int f = blockIdx.x;     // 0..FF-1
    float sx = 0.f, sy = 0.f;
    for (int rb = threadIdx.x; rb < NRB; rb += 256) {
        float2 v = part[(size_t)rb * PSTRIDE + f];
        sx += v.x; sy += v.y;
    }
    for (int off = 32; off >= 1; off >>= 1) {
        sx += __shfl_down(sx, off, 64);
        sy += __shfl_down(sy, off, 64);
    }
    __shared__ float red[2][4];
    int lane = threadIdx.x & 63, w = threadIdx.x >> 6;
    if (lane == 0) { red[0][w] = sx; red[1][w] = sy; }
    __syncthreads();
    if (threadIdx.x == 0) {
        sx = red[0][0]+red[0][1]+red[0][2]+red[0][3];
        sy = red[1][0]+red[1][1]+red[1][2]+red[1][3];
        echo[2*f] += sx;
        echo[2*f+1] += sy;
    }
}

// ---- irfft(n=1024) / fsm_window
__global__ void k_irfft(const float* __restrict__ echo, float* __restrict__ out) {
    int t = blockIdx.x * blockDim.x + threadIdx.x;   // 0..1023
    float acc = echo[0];                              // f=0 (real)
    float nyq = echo[2 * 512];                        // Nyquist real part
    acc += (t & 1) ? -nyq : nyq;
    for (int f = 1; f < 512; f++) {
        int m = (f * t) & 1023;
        float ang = (float)m * 0.006135923151542565f;  // 2*pi/1024
        float s, c; __sincosf(ang, &s, &c);
        acc += 2.0f * (echo[2*f]*c - echo[2*f+1]*s);
    }
    acc *= (1.0f / 1024.0f);
    float tsec = (float)t * (1.0f / 16000.0f);
    float win = expf(LOG_GAMMA * tsec);
    out[t] = acc / win;
}

extern "C" void kernel_launch(void* const* d_in, const int* in_sizes, int n_in,
                              void* d_out, int out_size, void* d_ws, size_t ws_size,
                              hipStream_t stream) {
    const float* source_pos   = (const float*)d_in[0];
    const float* receiver_pos = (const float*)d_in[1];
    const float* absorption   = (const float*)d_in[2];
    const float* scattering   = (const float*)d_in[3];
    const float* gk_val       = (const float*)d_in[4];
    const float* basis        = (const float*)d_in[5];
    const float* avg_dist     = (const float*)d_in[6];
    const float* rpos         = (const float*)d_in[7];
    const int*   gk_row       = (const int*)d_in[8];
    const int*   gk_col       = (const int*)d_in[9];
    const int*   object_ids   = (const int*)d_in[10];
    float* out = (float*)d_out;

    char* base = (char*)d_ws;
    size_t off = 0;
    auto alloc = [&](size_t bytes) -> void* {
        void* ptr = base + off;
        off = (off + bytes + 255) & ~(size_t)255;
        return ptr;
    };
    const size_t PLANE = (size_t)RR * FP2 + FP2;   // +1 row slack for tail-tile overread
    float*  Kt        = (float*)alloc(sizeof(float) * PP * DD * DD);
    float*  cur       = (float*)alloc(sizeof(float) * PLANE);
    float*  nxt       = (float*)alloc(sizeof(float) * PLANE);
    float*  per_row   = (float*)alloc(sizeof(float) * 6 * RR);
    int*    counts    = (int*)alloc(sizeof(int) * RR);
    int*    row_start = (int*)alloc(sizeof(int) * (RR + 1));
    int*    cursor    = (int*)alloc(sizeof(int) * RR);
    int2*   edge      = (int2*)alloc(sizeof(int2) * EE);
    float2* part      = (float2*)alloc(sizeof(float2) * NRB * PSTRIDE);
    float*  echo      = (float*)alloc(sizeof(float) * 1056);

    hipMemsetAsync(counts, 0, sizeof(int) * RR, stream);
    hipMemsetAsync(echo, 0, sizeof(float) * 1056, stream);
    hipMemsetAsync(part, 0, sizeof(float2) * NRB * PSTRIDE, stream);

    k_per_row<<<RR / 256, 256, 0, stream>>>(rpos, source_pos, receiver_pos, avg_dist, per_row);
    k_build_Kt<<<(PP * DD * DD) / 256, 256, 0, stream>>>(absorption, scattering, object_ids, basis, Kt);
    k_count<<<EE / 256, 256, 0, stream>>>(gk_row, counts);
    k_scan<<<1, 1024, 0, stream>>>(counts, row_start, cursor);
    k_scatter<<<EE / 256, 256, 0, stream>>>(gk_row, gk_val, gk_col, cursor, edge);
    k_init<<<dim3(9, 128), 256, 0, stream>>>(per_row, cur, echo);

    for (int b = 0; b < 4; b++) {
        k_matmul<<<2176, 256, 0, stream>>>(Kt, cur, per_row, nxt);
        k_segsum<<<NRB, 512, 0, stream>>>(row_start, edge, nxt, cur,
                                          per_row, part, (b < 3) ? 1 : 0);
    }

    k_fold<<<FF, 256, 0, stream>>>(part, echo);
    k_irfft<<<4, 256, 0, stream>>>(echo, out);
}

// Round 7
// 812.648 us; speedup vs baseline: 1.1852x; 1.1852x over previous
//
#include <hip/hip_runtime.h>
#include <math.h>

#define PP 128
#define DD 128
#define RR 16384
#define EE 131072
#define TT 1024
#define FF 513
#define FP 520          /* padded f count */
#define FP2 1040        /* floats per row (interleaved complex) */
#define KSTRIDE 132     /* LDS row stride for K tile: 16B-aligned, conflict-free */
#define NRB 4096        /* segsum row-blocks (4 rows each) */
#define PSTRIDE 528     /* part row stride in float2 */

#define TAU_SCALE 46.64723032069971    /* SR / C_SOUND */
#define KDECAY   -0.0211392282f        /* LOG_GAMMA/C - AIR */
#define LOG_GAMMA -6.907755278982137f
#define TWO_PI    6.283185307179586

__device__ __forceinline__ void pf_sincos(float tau, int f, float* s, float* c) {
    // phase = exp(-2*pi*i * tau * f / T); reduce in double, eval in float
    double rev = (double)tau * (double)f * (1.0 / 1024.0);
    rev -= floor(rev);
    float ang = (float)(-TWO_PI * rev);
    __sincosf(ang, s, c);
}

// ---- per-row precompute: amp_src, tau_src, amp_rec, tau_rec, dec_prop, tau_prop
__global__ void k_per_row(const float* __restrict__ rpos,
                          const float* __restrict__ spos,
                          const float* __restrict__ cpos,
                          const float* __restrict__ avg_dist,
                          float* __restrict__ per_row) {
    int r = blockIdx.x * blockDim.x + threadIdx.x;
    if (r >= RR) return;
    float x = rpos[3*r], y = rpos[3*r+1], z = rpos[3*r+2];

    float dx = x - spos[0], dy = y - spos[1], dz = z - spos[2];
    float ds = sqrtf(dx*dx + dy*dy + dz*dz);
    per_row[0*RR + r] = (1.0f/(ds*ds + 0.001f)) * expf(KDECAY * ds);
    per_row[1*RR + r] = ds * (float)TAU_SCALE;

    dx = x - cpos[0]; dy = y - cpos[1]; dz = z - cpos[2];
    float dr = sqrtf(dx*dx + dy*dy + dz*dz);
    per_row[2*RR + r] = (1.0f/(dr*dr + 0.001f)) * expf(KDECAY * dr);
    per_row[3*RR + r] = dr * (float)TAU_SCALE;

    float da = avg_dist[r];
    per_row[4*RR + r] = expf(KDECAY * da);
    per_row[5*RR + r] = da * (float)TAU_SCALE;
}

// ---- Kt[p][e][d] = refl*sc*basis0[d][e] + refl*(1-sc)*basis1[d][e]  (transposed)
__global__ void k_build_Kt(const float* __restrict__ absorption,
                           const float* __restrict__ scattering,
                           const int* __restrict__ object_ids,
                           const float* __restrict__ basis,
                           float* __restrict__ Kt) {
    int idx = blockIdx.x * 256 + threadIdx.x;   // p*16384 + e*128 + d
    int p = idx >> 14;
    int e = (idx >> 7) & 127;
    int d = idx & 127;
    int obj = object_ids[p];
    float refl = 1.0f - absorption[obj];
    float sc   = scattering[obj];
    int de = d * 128 + e;
    Kt[idx] = refl*sc*basis[de] + refl*(1.0f - sc)*basis[16384 + de];
}

// ---- CSR build
__global__ void k_count(const int* __restrict__ gk_row, int* __restrict__ counts) {
    int e = blockIdx.x * 256 + threadIdx.x;
    atomicAdd(&counts[gk_row[e]], 1);
}

__global__ __launch_bounds__(1024) void k_scan(const int* __restrict__ counts,
                                               int* __restrict__ row_start,
                                               int* __restrict__ cursor) {
    __shared__ int sh[1024];
    int tid = threadIdx.x;
    int base = tid * 16;
    int local[16];
    int sum = 0;
    #pragma unroll
    for (int j = 0; j < 16; j++) { local[j] = sum; sum += counts[base + j]; }
    sh[tid] = sum;
    __syncthreads();
    for (int off = 1; off < 1024; off <<= 1) {
        int v = (tid >= off) ? sh[tid - off] : 0;
        __syncthreads();
        sh[tid] += v;
        __syncthreads();
    }
    int chunk_excl = sh[tid] - sum;   // exclusive prefix of this 16-chunk
    #pragma unroll
    for (int j = 0; j < 16; j++) {
        int v = chunk_excl + local[j];
        row_start[base + j] = v;
        cursor[base + j] = v;
    }
    if (tid == 1023) row_start[RR] = chunk_excl + sum;
}

// scatter packing {col, val} per edge -> one b64 load in segsum
__global__ void k_scatter(const int* __restrict__ gk_row,
                          const float* __restrict__ gk_val,
                          const int* __restrict__ gk_col,
                          int* __restrict__ cursor,
                          int2* __restrict__ edge) {
    int e = blockIdx.x * 256 + threadIdx.x;
    int pos = atomicAdd(&cursor[gk_row[e]], 1);
    edge[pos] = make_int2(gk_col[e], __float_as_int(gk_val[e]));
}

// ---- init: cur[r][f] = amp_src*phase(tau_src); fused rad receiver-echo
__global__ __launch_bounds__(256) void k_init(const float* __restrict__ per_row,
                                              float* __restrict__ cur,
                                              float* __restrict__ echo) {
    int fl = threadIdx.x & 63, rg = threadIdx.x >> 6;
    int f = blockIdx.x * 64 + fl;               // < 576
    float ar = 0.f, ai = 0.f;
    int r0 = blockIdx.y * 128;
    if (f < FP) {
        for (int k = rg; k < 128; k += 4) {
            int r = r0 + k;
            float amp = per_row[r], tau = per_row[RR + r];
            float s, c; pf_sincos(tau, f, &s, &c);
            float re = amp * c, im = amp * s;
            *(float2*)(cur + (size_t)r * FP2 + f * 2) = make_float2(re, im);
            if (f < FF) {
                float w = per_row[2*RR + r], taur = per_row[3*RR + r];
                float s2, c2; pf_sincos(taur, f, &s2, &c2);
                ar = fmaf(w, c2*re - s2*im, ar);
                ai = fmaf(w, c2*im + s2*re, ai);
            }
        }
    }
    __shared__ float sh[4][64][2];
    sh[rg][fl][0] = ar; sh[rg][fl][1] = ai;
    __syncthreads();
    if (rg == 0 && f < FF) {
        float sx = sh[0][fl][0]+sh[1][fl][0]+sh[2][fl][0]+sh[3][fl][0];
        float sy = sh[0][fl][1]+sh[1][fl][1]+sh[2][fl][1]+sh[3][fl][1];
        atomicAdd(&echo[2*f],   sx);
        atomicAdd(&echo[2*f+1], sy);
    }
}

// ---- matmul + prop: out[p*128+d][f] = prop * sum_e Kt[p][e][d] * in[p*128+e][f]
// 1-D grid 2176 = 128 p x 17 ftiles(32 f), XCD-swizzled. 256 thr = 16 dg(8 d)
// x 16 fp(2 complex f). Per 64-e chunk: K (33.8 KB) AND v (16 KB) staged in
// LDS -> inner loop is pure LDS (3 b128/e ~36cy) + 32 FMA (64cy): VALU-bound.
// v staged once per block kills the 16x-redundant global loads (L1/TA bound
// in R4-R6).
__global__ __launch_bounds__(256) void k_matmul(const float* __restrict__ Kt,
                                                const float* __restrict__ in,
                                                const float* __restrict__ per_row,
                                                float* __restrict__ out) {
    __shared__ float Klds[64 * KSTRIDE];     // [e][d], 33.8 KB
    __shared__ float4 vlds[64][16];          // [e][fp],  16 KB
    int b = blockIdx.x;
    int xcd = b & 7;
    int g = b >> 3;                 // 272 groups
    int p = (g / 17) * 8 + xcd;
    int ftile = g % 17;
    int tid = threadIdx.x;

    int fp = tid & 15;              // f-pair
    int dg = tid >> 4;              // 8-d group
    int f = (ftile << 5) + (fp << 1);
    float acc[8][4];
    #pragma unroll
    for (int j = 0; j < 8; j++) { acc[j][0]=0.f; acc[j][1]=0.f; acc[j][2]=0.f; acc[j][3]=0.f; }
    const float* kbase = Klds + (dg << 3);

    for (int chunk = 0; chunk < 2; chunk++) {
        const float4* Kp4 = (const float4*)(Kt + (p << 14) + (chunk << 13));
        const float* vsrc = in + (size_t)((p << 7) + (chunk << 6)) * FP2 + (ftile << 6);
        if (chunk) __syncthreads();           // protect readers of prev chunk
        for (int i = tid; i < 2048; i += 256) {
            float4 kv = Kp4[i];
            *(float4*)&Klds[(i >> 5) * KSTRIDE + ((i & 31) << 2)] = kv;
        }
        for (int i = tid; i < 1024; i += 256) {
            int e = i >> 4, fpi = i & 15;
            vlds[e][fpi] = *(const float4*)(vsrc + (size_t)e * FP2 + (fpi << 2));
        }
        __syncthreads();
        #pragma unroll 4
        for (int ee = 0; ee < 64; ee++) {
            float4 v = vlds[ee][fp];
            const float* kr = kbase + ee * KSTRIDE;
            #pragma unroll
            for (int j = 0; j < 8; j++) {
                float kv = kr[j];
                acc[j][0] = fmaf(kv, v.x, acc[j][0]);
                acc[j][1] = fmaf(kv, v.y, acc[j][1]);
                acc[j][2] = fmaf(kv, v.z, acc[j][2]);
                acc[j][3] = fmaf(kv, v.w, acc[j][3]);
            }
        }
    }
    if (f < FP) {                   // f<=518: stores f, f+1 both valid
        int d0 = dg << 3;
        #pragma unroll
        for (int j = 0; j < 8; j++) {
            int row = (p << 7) + d0 + j;
            float dec = per_row[4*RR + row];
            float tau = per_row[5*RR + row];
            float s0,c0,s1,c1;
            pf_sincos(tau, f,   &s0, &c0);
            pf_sincos(tau, f+1, &s1, &c1);
            float4 o;
            o.x = dec*(acc[j][0]*c0 - acc[j][1]*s0);
            o.y = dec*(acc[j][1]*c0 + acc[j][0]*s0);
            o.z = dec*(acc[j][2]*c1 - acc[j][3]*s1);
            o.w = dec*(acc[j][3]*c1 + acc[j][2]*s1);
            *(float4*)(out + (size_t)row * FP2 + f * 2) = o;
        }
    }
}

// ---- segment sum + fused receiver-echo epilogue.
// 4096 blocks x 512 thr = 128 fl x 4 ry. Each lane: 4 f-slices (fl, fl+128,
// fl+256, fl+384) + tail (fl<8: 512+fl). Echo partials reduced over the 4 rows
// in LDS, accumulated (non-atomic) into part[rowblk][f]; k_fold sums at end.
__global__ __launch_bounds__(512) void k_segsum(const int* __restrict__ row_start,
                                                const int2* __restrict__ edge,
                                                const float* __restrict__ in,
                                                float* __restrict__ outp,
                                                const float* __restrict__ per_row,
                                                float2* __restrict__ part,
                                                int store_cur) {
    __shared__ float2 sh[4][128][5];
    int rb = blockIdx.x;
    int fl = threadIdx.x & 127, ry = threadIdx.x >> 7;
    int row = (rb << 2) + ry;
    int s0 = row_start[row], s1 = row_start[row + 1];
    float a0r=0.f,a0i=0.f,a1r=0.f,a1i=0.f,a2r=0.f,a2i=0.f,a3r=0.f,a3i=0.f;
    float t4r=0.f,t4i=0.f;
    bool tail = (fl < 8);
    for (int t = s0; t < s1; t++) {
        int2 ed = edge[t];
        float v = __int_as_float(ed.y);
        const float* g = in + (size_t)ed.x * FP2 + fl * 2;
        float2 g0 = *(const float2*)(g);
        float2 g1 = *(const float2*)(g + 256);
        float2 g2 = *(const float2*)(g + 512);
        float2 g3 = *(const float2*)(g + 768);
        a0r = fmaf(v, g0.x, a0r); a0i = fmaf(v, g0.y, a0i);
        a1r = fmaf(v, g1.x, a1r); a1i = fmaf(v, g1.y, a1i);
        a2r = fmaf(v, g2.x, a2r); a2i = fmaf(v, g2.y, a2i);
        a3r = fmaf(v, g3.x, a3r); a3i = fmaf(v, g3.y, a3i);
        if (tail) {
            float2 g4 = *(const float2*)(g + 1024);
            t4r = fmaf(v, g4.x, t4r); t4i = fmaf(v, g4.y, t4i);
        }
    }
    if (store_cur) {
        float* w = outp + (size_t)row * FP2 + fl * 2;
        *(float2*)(w)        = make_float2(a0r, a0i);
        *(float2*)(w + 256)  = make_float2(a1r, a1i);
        *(float2*)(w + 512)  = make_float2(a2r, a2i);
        *(float2*)(w + 768)  = make_float2(a3r, a3i);
        if (tail) *(float2*)(w + 1024) = make_float2(t4r, t4i);
    }
    // echo epilogue: contrib(f) = w_rec * phase(tau_rec, f) * value
    float wr = per_row[2*RR + row], taur = per_row[3*RR + row];
    {
        float s, c;
        pf_sincos(taur, fl, &s, &c);
        sh[ry][fl][0] = make_float2(wr*(c*a0r - s*a0i), wr*(c*a0i + s*a0r));
        pf_sincos(taur, fl + 128, &s, &c);
        sh[ry][fl][1] = make_float2(wr*(c*a1r - s*a1i), wr*(c*a1i + s*a1r));
        pf_sincos(taur, fl + 256, &s, &c);
        sh[ry][fl][2] = make_float2(wr*(c*a2r - s*a2i), wr*(c*a2i + s*a2r));
        pf_sincos(taur, fl + 384, &s, &c);
        sh[ry][fl][3] = make_float2(wr*(c*a3r - s*a3i), wr*(c*a3i + s*a3r));
        float2 c4 = make_float2(0.f, 0.f);
        if (tail && (512 + fl) < FF) {       // f=512 only
            pf_sincos(taur, 512 + fl, &s, &c);
            c4 = make_float2(wr*(c*t4r - s*t4i), wr*(c*t4i + s*t4r));
        }
        sh[ry][fl][4] = c4;
    }
    __syncthreads();
    if (ry == 0) {
        float2* pp = part + (size_t)rb * PSTRIDE;
        #pragma unroll
        for (int sidx = 0; sidx < 5; sidx++) {
            int fidx = sidx * 128 + fl;
            if (fidx < FP) {
                float2 v0 = sh[0][fl][sidx], v1 = sh[1][fl][sidx];
                float2 v2 = sh[2][fl][sidx], v3 = sh[3][fl][sidx];
                float2 acc = pp[fidx];
                acc.x += v0.x + v1.x + v2.x + v3.x;
                acc.y += v0.y + v1.y + v2.y + v3.y;
                pp[fidx] = acc;
            }
        }
    }
}

// ---- fold echo partials: echo[f] += sum_rb part[rb][f]
__global__ __launch_bounds__(256) void k_fold(const float2* __restrict__ part,
                                              float* __restrict__ echo) {
    int f = blockIdx.x;     // 0..FF-1
    float sx = 0.f, sy = 0.f;
    for (int rb = threadIdx.x; rb < NRB; rb += 256) {
        float2 v = part[(size_t)rb * PSTRIDE + f];
        sx += v.x; sy += v.y;
    }
    for (int off = 32; off >= 1; off >>= 1) {
        sx += __shfl_down(sx, off, 64);
        sy += __shfl_down(sy, off, 64);
    }
    __shared__ float red[2][4];
    int lane = threadIdx.x & 63, w = threadIdx.x >> 6;
    if (lane == 0) { red[0][w] = sx; red[1][w] = sy; }
    __syncthreads();
    if (threadIdx.x == 0) {
        sx = red[0][0]+red[0][1]+red[0][2]+red[0][3];
        sy = red[1][0]+red[1][1]+red[1][2]+red[1][3];
        echo[2*f] += sx;
        echo[2*f+1] += sy;
    }
}

// ---- irfft(n=1024) / fsm_window
__global__ void k_irfft(const float* __restrict__ echo, float* __restrict__ out) {
    int t = blockIdx.x * blockDim.x + threadIdx.x;   // 0..1023
    float acc = echo[0];                              // f=0 (real)
    float nyq = echo[2 * 512];                        // Nyquist real part
    acc += (t & 1) ? -nyq : nyq;
    for (int f = 1; f < 512; f++) {
        int m = (f * t) & 1023;
        float ang = (float)m * 0.006135923151542565f;  // 2*pi/1024
        float s, c; __sincosf(ang, &s, &c);
        acc += 2.0f * (echo[2*f]*c - echo[2*f+1]*s);
    }
    acc *= (1.0f / 1024.0f);
    float tsec = (float)t * (1.0f / 16000.0f);
    float win = expf(LOG_GAMMA * tsec);
    out[t] = acc / win;
}

extern "C" void kernel_launch(void* const* d_in, const int* in_sizes, int n_in,
                              void* d_out, int out_size, void* d_ws, size_t ws_size,
                              hipStream_t stream) {
    const float* source_pos   = (const float*)d_in[0];
    const float* receiver_pos = (const float*)d_in[1];
    const float* absorption   = (const float*)d_in[2];
    const float* scattering   = (const float*)d_in[3];
    const float* gk_val       = (const float*)d_in[4];
    const float* basis        = (const float*)d_in[5];
    const float* avg_dist     = (const float*)d_in[6];
    const float* rpos         = (const float*)d_in[7];
    const int*   gk_row       = (const int*)d_in[8];
    const int*   gk_col       = (const int*)d_in[9];
    const int*   object_ids   = (const int*)d_in[10];
    float* out = (float*)d_out;

    char* base = (char*)d_ws;
    size_t off = 0;
    auto alloc = [&](size_t bytes) -> void* {
        void* ptr = base + off;
        off = (off + bytes + 255) & ~(size_t)255;
        return ptr;
    };
    const size_t PLANE = (size_t)RR * FP2 + FP2;   // +1 row slack for tail-tile overread
    float*  Kt        = (float*)alloc(sizeof(float) * PP * DD * DD);
    float*  cur       = (float*)alloc(sizeof(float) * PLANE);
    float*  nxt       = (float*)alloc(sizeof(float) * PLANE);
    float*  per_row   = (float*)alloc(sizeof(float) * 6 * RR);
    int*    counts    = (int*)alloc(sizeof(int) * RR);
    int*    row_start = (int*)alloc(sizeof(int) * (RR + 1));
    int*    cursor    = (int*)alloc(sizeof(int) * RR);
    int2*   edge      = (int2*)alloc(sizeof(int2) * EE);
    float2* part      = (float2*)alloc(sizeof(float2) * NRB * PSTRIDE);
    float*  echo      = (float*)alloc(sizeof(float) * 1056);

    hipMemsetAsync(counts, 0, sizeof(int) * RR, stream);
    hipMemsetAsync(echo, 0, sizeof(float) * 1056, stream);
    hipMemsetAsync(part, 0, sizeof(float2) * NRB * PSTRIDE, stream);

    k_per_row<<<RR / 256, 256, 0, stream>>>(rpos, source_pos, receiver_pos, avg_dist, per_row);
    k_build_Kt<<<(PP * DD * DD) / 256, 256, 0, stream>>>(absorption, scattering, object_ids, basis, Kt);
    k_count<<<EE / 256, 256, 0, stream>>>(gk_row, counts);
    k_scan<<<1, 1024, 0, stream>>>(counts, row_start, cursor);
    k_scatter<<<EE / 256, 256, 0, stream>>>(gk_row, gk_val, gk_col, cursor, edge);
    k_init<<<dim3(9, 128), 256, 0, stream>>>(per_row, cur, echo);

    for (int b = 0; b < 4; b++) {
        k_matmul<<<2176, 256, 0, stream>>>(Kt, cur, per_row, nxt);
        k_segsum<<<NRB, 512, 0, stream>>>(row_start, edge, nxt, cur,
                                          per_row, part, (b < 3) ? 1 : 0);
    }

    k_fold<<<FF, 256, 0, stream>>>(part, echo);
    k_irfft<<<4, 256, 0, stream>>>(echo, out);
}

// Round 8
// 713.475 us; speedup vs baseline: 1.3499x; 1.1390x over previous
//
#include <hip/hip_runtime.h>
#include <math.h>

#define PP 128
#define DD 128
#define RR 16384
#define EE 131072
#define TT 1024
#define FF 513
#define FP 520          /* padded f count */
#define FP2 1040        /* floats per row (interleaved complex) */
#define NRB 4096        /* segsum row-blocks (4 rows each) */
#define PSTRIDE 528     /* part row stride in float2 */
#define VSTRIDE 18      /* LDS V-tile row stride (floats): even, <=2-way banks */

#define TAU_SCALE 46.64723032069971    /* SR / C_SOUND */
#define KDECAY   -0.0211392282f        /* LOG_GAMMA/C - AIR */
#define LOG_GAMMA -6.907755278982137f
#define TWO_PI    6.283185307179586

typedef __attribute__((ext_vector_type(8))) short bf16x8;
typedef __attribute__((ext_vector_type(4))) float f32x4;

__device__ __forceinline__ short f2bf(float x) {       // RNE float->bf16 bits
    unsigned u = __float_as_uint(x);
    unsigned r = (u + 0x7fffu + ((u >> 16) & 1u)) >> 16;
    return (short)r;
}
__device__ __forceinline__ float bf2f(short b) {
    return __uint_as_float(((unsigned)(unsigned short)b) << 16);
}

__device__ __forceinline__ void pf_sincos(float tau, int f, float* s, float* c) {
    // phase = exp(-2*pi*i * tau * f / T); reduce in double, eval in float
    double rev = (double)tau * (double)f * (1.0 / 1024.0);
    rev -= floor(rev);
    float ang = (float)(-TWO_PI * rev);
    __sincosf(ang, s, c);
}

// ---- per-row precompute: amp_src, tau_src, amp_rec, tau_rec, dec_prop, tau_prop
__global__ void k_per_row(const float* __restrict__ rpos,
                          const float* __restrict__ spos,
                          const float* __restrict__ cpos,
                          const float* __restrict__ avg_dist,
                          float* __restrict__ per_row) {
    int r = blockIdx.x * blockDim.x + threadIdx.x;
    if (r >= RR) return;
    float x = rpos[3*r], y = rpos[3*r+1], z = rpos[3*r+2];

    float dx = x - spos[0], dy = y - spos[1], dz = z - spos[2];
    float ds = sqrtf(dx*dx + dy*dy + dz*dz);
    per_row[0*RR + r] = (1.0f/(ds*ds + 0.001f)) * expf(KDECAY * ds);
    per_row[1*RR + r] = ds * (float)TAU_SCALE;

    dx = x - cpos[0]; dy = y - cpos[1]; dz = z - cpos[2];
    float dr = sqrtf(dx*dx + dy*dy + dz*dz);
    per_row[2*RR + r] = (1.0f/(dr*dr + 0.001f)) * expf(KDECAY * dr);
    per_row[3*RR + r] = dr * (float)TAU_SCALE;

    float da = avg_dist[r];
    per_row[4*RR + r] = expf(KDECAY * da);
    per_row[5*RR + r] = da * (float)TAU_SCALE;
}

// ---- K[p][d][e] = refl*sc*basis0[d][e] + refl*(1-sc)*basis1[d][e]
__global__ void k_build_K(const float* __restrict__ absorption,
                          const float* __restrict__ scattering,
                          const int* __restrict__ object_ids,
                          const float* __restrict__ basis,
                          float* __restrict__ Kmat) {
    int idx = blockIdx.x * 256 + threadIdx.x;   // p*16384 + d*128 + e
    int p  = idx >> 14;
    int de = idx & 16383;
    int obj = object_ids[p];
    float refl = 1.0f - absorption[obj];
    float sc   = scattering[obj];
    Kmat[idx] = refl*sc*basis[de] + refl*(1.0f - sc)*basis[16384 + de];
}

// ---- CSR build
__global__ void k_count(const int* __restrict__ gk_row, int* __restrict__ counts) {
    int e = blockIdx.x * 256 + threadIdx.x;
    atomicAdd(&counts[gk_row[e]], 1);
}

__global__ __launch_bounds__(1024) void k_scan(const int* __restrict__ counts,
                                               int* __restrict__ row_start,
                                               int* __restrict__ cursor) {
    __shared__ int sh[1024];
    int tid = threadIdx.x;
    int base = tid * 16;
    int local[16];
    int sum = 0;
    #pragma unroll
    for (int j = 0; j < 16; j++) { local[j] = sum; sum += counts[base + j]; }
    sh[tid] = sum;
    __syncthreads();
    for (int off = 1; off < 1024; off <<= 1) {
        int v = (tid >= off) ? sh[tid - off] : 0;
        __syncthreads();
        sh[tid] += v;
        __syncthreads();
    }
    int chunk_excl = sh[tid] - sum;   // exclusive prefix of this 16-chunk
    #pragma unroll
    for (int j = 0; j < 16; j++) {
        int v = chunk_excl + local[j];
        row_start[base + j] = v;
        cursor[base + j] = v;
    }
    if (tid == 1023) row_start[RR] = chunk_excl + sum;
}

// scatter packing {col, val} per edge -> one b64 load in segsum
__global__ void k_scatter(const int* __restrict__ gk_row,
                          const float* __restrict__ gk_val,
                          const int* __restrict__ gk_col,
                          int* __restrict__ cursor,
                          int2* __restrict__ edge) {
    int e = blockIdx.x * 256 + threadIdx.x;
    int pos = atomicAdd(&cursor[gk_row[e]], 1);
    edge[pos] = make_int2(gk_col[e], __float_as_int(gk_val[e]));
}

// ---- init: cur[r][f] = amp_src*phase(tau_src); fused rad receiver-echo
__global__ __launch_bounds__(256) void k_init(const float* __restrict__ per_row,
                                              float* __restrict__ cur,
                                              float* __restrict__ echo) {
    int fl = threadIdx.x & 63, rg = threadIdx.x >> 6;
    int f = blockIdx.x * 64 + fl;               // < 576
    float ar = 0.f, ai = 0.f;
    int r0 = blockIdx.y * 128;
    if (f < FP) {
        for (int k = rg; k < 128; k += 4) {
            int r = r0 + k;
            float amp = per_row[r], tau = per_row[RR + r];
            float s, c; pf_sincos(tau, f, &s, &c);
            float re = amp * c, im = amp * s;
            *(float2*)(cur + (size_t)r * FP2 + f * 2) = make_float2(re, im);
            if (f < FF) {
                float w = per_row[2*RR + r], taur = per_row[3*RR + r];
                float s2, c2; pf_sincos(taur, f, &s2, &c2);
                ar = fmaf(w, c2*re - s2*im, ar);
                ai = fmaf(w, c2*im + s2*re, ai);
            }
        }
    }
    __shared__ float sh[4][64][2];
    sh[rg][fl][0] = ar; sh[rg][fl][1] = ai;
    __syncthreads();
    if (rg == 0 && f < FF) {
        float sx = sh[0][fl][0]+sh[1][fl][0]+sh[2][fl][0]+sh[3][fl][0];
        float sy = sh[0][fl][1]+sh[1][fl][1]+sh[2][fl][1]+sh[3][fl][1];
        atomicAdd(&echo[2*f],   sx);
        atomicAdd(&echo[2*f+1], sy);
    }
}

// ---- matmul + prop via bf16x2-split MFMA.
// out[p] = K[p] (128x128 real) x V[p] (128x1040 reals). Split K,V into bf16
// hi/lo; acc = AhBh + AhBl + AlBh (AlBl ~ 2^-18 dropped) on
// mfma_f32_16x16x32_bf16. Grid 512 = 128 p x 4 n-chunks (XCD-swizzled on p).
// Block 256 thr = 4 waves; wave w owns M-tiles {2w, 2w+1}; A-frags + dec/tau
// preloaded once. V per 16-col tile staged via double-buffered LDS.
// Layouts (HW-verified): A[m=lane&15][k=quad*8+j]; C/D col=lane&15,
// row=quad*4+reg; B mirrors A on columns. Epilogue pairs re/im via shfl_xor(1).
__global__ __launch_bounds__(256) void k_matmul(const float* __restrict__ Kmat,
                                                const float* __restrict__ in,
                                                const float* __restrict__ per_row,
                                                float* __restrict__ out) {
    __shared__ float vlds[2][128 * VSTRIDE];
    int b = blockIdx.x;
    int xcd = b & 7;
    int g = b >> 3;                  // 0..63
    int p = (g >> 2) * 8 + xcd;
    int nq = g & 3;
    int nt0 = nq * 16;
    int ntEnd = (nq == 3) ? 65 : nt0 + 16;

    int tid  = threadIdx.x;
    int wave = tid >> 6;
    int lane = tid & 63;
    int quad = lane >> 4;
    int n    = lane & 15;
    int mt0  = wave << 1;

    // A fragments (hi/lo) for this wave's two M-tiles, all 4 K-tiles
    bf16x8 Ah[2][4], Al[2][4];
    #pragma unroll
    for (int mi = 0; mi < 2; mi++) {
        const float* kp = Kmat + (p << 14) + ((mt0 + mi) * 16 + n) * 128 + quad * 8;
        #pragma unroll
        for (int kt = 0; kt < 4; kt++) {
            float4 x0 = *(const float4*)(kp + kt * 32);
            float4 x1 = *(const float4*)(kp + kt * 32 + 4);
            float xs[8] = {x0.x,x0.y,x0.z,x0.w,x1.x,x1.y,x1.z,x1.w};
            bf16x8 h, l;
            #pragma unroll
            for (int j = 0; j < 8; j++) {
                short hb = f2bf(xs[j]);
                h[j] = hb;
                l[j] = f2bf(xs[j] - bf2f(hb));
            }
            Ah[mi][kt] = h; Al[mi][kt] = l;
        }
    }
    // per-output-row prop constants (row within tile = quad*4 + reg)
    float dec_[2][4], tau_[2][4];
    #pragma unroll
    for (int mi = 0; mi < 2; mi++)
        #pragma unroll
        for (int r = 0; r < 4; r++) {
            int row = (p << 7) + (mt0 + mi) * 16 + quad * 4 + r;
            dec_[mi][r] = per_row[4*RR + row];
            tau_[mi][r] = per_row[5*RR + row];
        }

    const float* pin = in + (size_t)(p << 7) * FP2;
    float4 pf0, pf1;
    int se = tid >> 2, sc4 = (tid & 3) * 4;      // staging: e-row, col4
    auto loadTile = [&](int nt) {
        const float* src = pin + nt * 16 + sc4;
        pf0 = *(const float4*)(src + (size_t)se * FP2);
        pf1 = *(const float4*)(src + (size_t)(se + 64) * FP2);
    };
    auto writeTile = [&](int buf) {
        float* dst = &vlds[buf][0];
        *(float2*)(dst + se*VSTRIDE + sc4)            = make_float2(pf0.x, pf0.y);
        *(float2*)(dst + se*VSTRIDE + sc4 + 2)        = make_float2(pf0.z, pf0.w);
        *(float2*)(dst + (se+64)*VSTRIDE + sc4)       = make_float2(pf1.x, pf1.y);
        *(float2*)(dst + (se+64)*VSTRIDE + sc4 + 2)   = make_float2(pf1.z, pf1.w);
    };

    loadTile(nt0); writeTile(0);
    for (int nt = nt0; nt < ntEnd; nt++) {
        int cb = (nt - nt0) & 1;
        __syncthreads();                    // vlds[cb] ready for read
        if (nt + 1 < ntEnd) { loadTile(nt + 1); writeTile(cb ^ 1); }

        f32x4 acc0 = {0.f,0.f,0.f,0.f}, acc1 = {0.f,0.f,0.f,0.f};
        const float* vb = &vlds[cb][0];
        #pragma unroll
        for (int kt = 0; kt < 4; kt++) {
            bf16x8 Bh, Bl;
            #pragma unroll
            for (int j = 0; j < 8; j++) {
                float x = vb[(kt*32 + quad*8 + j) * VSTRIDE + n];
                short hb = f2bf(x);
                Bh[j] = hb;
                Bl[j] = f2bf(x - bf2f(hb));
            }
            acc0 = __builtin_amdgcn_mfma_f32_16x16x32_bf16(Ah[0][kt], Bh, acc0, 0,0,0);
            acc1 = __builtin_amdgcn_mfma_f32_16x16x32_bf16(Ah[1][kt], Bh, acc1, 0,0,0);
            acc0 = __builtin_amdgcn_mfma_f32_16x16x32_bf16(Ah[0][kt], Bl, acc0, 0,0,0);
            acc1 = __builtin_amdgcn_mfma_f32_16x16x32_bf16(Ah[1][kt], Bl, acc1, 0,0,0);
            acc0 = __builtin_amdgcn_mfma_f32_16x16x32_bf16(Al[0][kt], Bh, acc0, 0,0,0);
            acc1 = __builtin_amdgcn_mfma_f32_16x16x32_bf16(Al[1][kt], Bh, acc1, 0,0,0);
        }

        // prop epilogue: complex rotate via re/im partner in adjacent lane
        int nfl = nt * 16 + n;              // float index in row, < 1040
        int f   = nfl >> 1;
        bool odd = nfl & 1;
        #pragma unroll
        for (int mi = 0; mi < 2; mi++) {
            f32x4 a = mi ? acc1 : acc0;
            #pragma unroll
            for (int r = 0; r < 4; r++) {
                float av = a[r];
                float pv = __shfl_xor(av, 1);
                float s, c; pf_sincos(tau_[mi][r], f, &s, &c);
                float o = dec_[mi][r] * (odd ? fmaf(av, c,  s*pv)
                                             : fmaf(av, c, -s*pv));
                int row = (p << 7) + (mt0 + mi) * 16 + quad * 4 + r;
                out[(size_t)row * FP2 + nfl] = o;
            }
        }
    }
}

// ---- segment sum + fused receiver-echo epilogue.
// 4096 blocks x 512 thr = 128 fl x 4 ry. Each lane: 4 f-slices (fl, fl+128,
// fl+256, fl+384) + tail (fl<8: 512+fl). Echo partials reduced over the 4 rows
// in LDS, accumulated (non-atomic) into part[rowblk][f]; k_fold sums at end.
__global__ __launch_bounds__(512) void k_segsum(const int* __restrict__ row_start,
                                                const int2* __restrict__ edge,
                                                const float* __restrict__ in,
                                                float* __restrict__ outp,
                                                const float* __restrict__ per_row,
                                                float2* __restrict__ part,
                                                int store_cur) {
    __shared__ float2 sh[4][128][5];
    int rb = blockIdx.x;
    int fl = threadIdx.x & 127, ry = threadIdx.x >> 7;
    int row = (rb << 2) + ry;
    int s0 = row_start[row], s1 = row_start[row + 1];
    float a0r=0.f,a0i=0.f,a1r=0.f,a1i=0.f,a2r=0.f,a2i=0.f,a3r=0.f,a3i=0.f;
    float t4r=0.f,t4i=0.f;
    bool tail = (fl < 8);
    for (int t = s0; t < s1; t++) {
        int2 ed = edge[t];
        float v = __int_as_float(ed.y);
        const float* g = in + (size_t)ed.x * FP2 + fl * 2;
        float2 g0 = *(const float2*)(g);
        float2 g1 = *(const float2*)(g + 256);
        float2 g2 = *(const float2*)(g + 512);
        float2 g3 = *(const float2*)(g + 768);
        a0r = fmaf(v, g0.x, a0r); a0i = fmaf(v, g0.y, a0i);
        a1r = fmaf(v, g1.x, a1r); a1i = fmaf(v, g1.y, a1i);
        a2r = fmaf(v, g2.x, a2r); a2i = fmaf(v, g2.y, a2i);
        a3r = fmaf(v, g3.x, a3r); a3i = fmaf(v, g3.y, a3i);
        if (tail) {
            float2 g4 = *(const float2*)(g + 1024);
            t4r = fmaf(v, g4.x, t4r); t4i = fmaf(v, g4.y, t4i);
        }
    }
    if (store_cur) {
        float* w = outp + (size_t)row * FP2 + fl * 2;
        *(float2*)(w)        = make_float2(a0r, a0i);
        *(float2*)(w + 256)  = make_float2(a1r, a1i);
        *(float2*)(w + 512)  = make_float2(a2r, a2i);
        *(float2*)(w + 768)  = make_float2(a3r, a3i);
        if (tail) *(float2*)(w + 1024) = make_float2(t4r, t4i);
    }
    // echo epilogue: contrib(f) = w_rec * phase(tau_rec, f) * value
    float wr = per_row[2*RR + row], taur = per_row[3*RR + row];
    {
        float s, c;
        pf_sincos(taur, fl, &s, &c);
        sh[ry][fl][0] = make_float2(wr*(c*a0r - s*a0i), wr*(c*a0i + s*a0r));
        pf_sincos(taur, fl + 128, &s, &c);
        sh[ry][fl][1] = make_float2(wr*(c*a1r - s*a1i), wr*(c*a1i + s*a1r));
        pf_sincos(taur, fl + 256, &s, &c);
        sh[ry][fl][2] = make_float2(wr*(c*a2r - s*a2i), wr*(c*a2i + s*a2r));
        pf_sincos(taur, fl + 384, &s, &c);
        sh[ry][fl][3] = make_float2(wr*(c*a3r - s*a3i), wr*(c*a3i + s*a3r));
        float2 c4 = make_float2(0.f, 0.f);
        if (tail && (512 + fl) < FF) {       // f=512 only
            pf_sincos(taur, 512 + fl, &s, &c);
            c4 = make_float2(wr*(c*t4r - s*t4i), wr*(c*t4i + s*t4r));
        }
        sh[ry][fl][4] = c4;
    }
    __syncthreads();
    if (ry == 0) {
        float2* pp = part + (size_t)rb * PSTRIDE;
        #pragma unroll
        for (int sidx = 0; sidx < 5; sidx++) {
            int fidx = sidx * 128 + fl;
            if (fidx < FP) {
                float2 v0 = sh[0][fl][sidx], v1 = sh[1][fl][sidx];
                float2 v2 = sh[2][fl][sidx], v3 = sh[3][fl][sidx];
                float2 acc = pp[fidx];
                acc.x += v0.x + v1.x + v2.x + v3.x;
                acc.y += v0.y + v1.y + v2.y + v3.y;
                pp[fidx] = acc;
            }
        }
    }
}

// ---- fold echo partials: echo[f] += sum_rb part[rb][f]
__global__ __launch_bounds__(256) void k_fold(const float2* __restrict__ part,
                                              float* __restrict__ echo) {
    int f = blockIdx.x;     // 0..FF-1
    float sx = 0.f, sy = 0.f;
    for (int rb = threadIdx.x; rb < NRB; rb += 256) {
        float2 v = part[(size_t)rb * PSTRIDE + f];
        sx += v.x; sy += v.y;
    }
    for (int off = 32; off >= 1; off >>= 1) {
        sx += __shfl_down(sx, off, 64);
        sy += __shfl_down(sy, off, 64);
    }
    __shared__ float red[2][4];
    int lane = threadIdx.x & 63, w = threadIdx.x >> 6;
    if (lane == 0) { red[0][w] = sx; red[1][w] = sy; }
    __syncthreads();
    if (threadIdx.x == 0) {
        sx = red[0][0]+red[0][1]+red[0][2]+red[0][3];
        sy = red[1][0]+red[1][1]+red[1][2]+red[1][3];
        echo[2*f] += sx;
        echo[2*f+1] += sy;
    }
}

// ---- irfft(n=1024) / fsm_window
__global__ void k_irfft(const float* __restrict__ echo, float* __restrict__ out) {
    int t = blockIdx.x * blockDim.x + threadIdx.x;   // 0..1023
    float acc = echo[0];                              // f=0 (real)
    float nyq = echo[2 * 512];                        // Nyquist real part
    acc += (t & 1) ? -nyq : nyq;
    for (int f = 1; f < 512; f++) {
        int m = (f * t) & 1023;
        float ang = (float)m * 0.006135923151542565f;  // 2*pi/1024
        float s, c; __sincosf(ang, &s, &c);
        acc += 2.0f * (echo[2*f]*c - echo[2*f+1]*s);
    }
    acc *= (1.0f / 1024.0f);
    float tsec = (float)t * (1.0f / 16000.0f);
    float win = expf(LOG_GAMMA * tsec);
    out[t] = acc / win;
}

extern "C" void kernel_launch(void* const* d_in, const int* in_sizes, int n_in,
                              void* d_out, int out_size, void* d_ws, size_t ws_size,
                              hipStream_t stream) {
    const float* source_pos   = (const float*)d_in[0];
    const float* receiver_pos = (const float*)d_in[1];
    const float* absorption   = (const float*)d_in[2];
    const float* scattering   = (const float*)d_in[3];
    const float* gk_val       = (const float*)d_in[4];
    const float* basis        = (const float*)d_in[5];
    const float* avg_dist     = (const float*)d_in[6];
    const float* rpos         = (const float*)d_in[7];
    const int*   gk_row       = (const int*)d_in[8];
    const int*   gk_col       = (const int*)d_in[9];
    const int*   object_ids   = (const int*)d_in[10];
    float* out = (float*)d_out;

    char* base = (char*)d_ws;
    size_t off = 0;
    auto alloc = [&](size_t bytes) -> void* {
        void* ptr = base + off;
        off = (off + bytes + 255) & ~(size_t)255;
        return ptr;
    };
    const size_t PLANE = (size_t)RR * FP2 + FP2;   // +1 row slack
    float*  Kmat      = (float*)alloc(sizeof(float) * PP * DD * DD);
    float*  cur       = (float*)alloc(sizeof(float) * PLANE);
    float*  nxt       = (float*)alloc(sizeof(float) * PLANE);
    float*  per_row   = (float*)alloc(sizeof(float) * 6 * RR);
    int*    counts    = (int*)alloc(sizeof(int) * RR);
    int*    row_start = (int*)alloc(sizeof(int) * (RR + 1));
    int*    cursor    = (int*)alloc(sizeof(int) * RR);
    int2*   edge      = (int2*)alloc(sizeof(int2) * EE);
    float2* part      = (float2*)alloc(sizeof(float2) * NRB * PSTRIDE);
    float*  echo      = (float*)alloc(sizeof(float) * 1056);

    hipMemsetAsync(counts, 0, sizeof(int) * RR, stream);
    hipMemsetAsync(echo, 0, sizeof(float) * 1056, stream);
    hipMemsetAsync(part, 0, sizeof(float2) * NRB * PSTRIDE, stream);

    k_per_row<<<RR / 256, 256, 0, stream>>>(rpos, source_pos, receiver_pos, avg_dist, per_row);
    k_build_K<<<(PP * DD * DD) / 256, 256, 0, stream>>>(absorption, scattering, object_ids, basis, Kmat);
    k_count<<<EE / 256, 256, 0, stream>>>(gk_row, counts);
    k_scan<<<1, 1024, 0, stream>>>(counts, row_start, cursor);
    k_scatter<<<EE / 256, 256, 0, stream>>>(gk_row, gk_val, gk_col, cursor, edge);
    k_init<<<dim3(9, 128), 256, 0, stream>>>(per_row, cur, echo);

    for (int b = 0; b < 4; b++) {
        k_matmul<<<512, 256, 0, stream>>>(Kmat, cur, per_row, nxt);
        k_segsum<<<NRB, 512, 0, stream>>>(row_start, edge, nxt, cur,
                                          per_row, part, (b < 3) ? 1 : 0);
    }

    k_fold<<<FF, 256, 0, stream>>>(part, echo);
    k_irfft<<<4, 256, 0, stream>>>(echo, out);
}

// Round 9
// 548.657 us; speedup vs baseline: 1.7554x; 1.3004x over previous
//
#include <hip/hip_runtime.h>
#include <math.h>

#define PP 128
#define DD 128
#define RR 16384
#define EE 131072
#define TT 1024
#define FF 513
#define FP 520          /* padded f count */
#define FP2 1040        /* bf16 elems per row (interleaved complex) */
#define NRB 4096        /* segsum row-blocks (4 rows each) */
#define PSTRIDE 528     /* part row stride in float2 */
#define VSTRIDE 18      /* LDS V-tile row stride (floats): conflict-free */

#define TAU_SCALE 46.64723032069971    /* SR / C_SOUND */
#define KDECAY   -0.0211392282f        /* LOG_GAMMA/C - AIR */
#define LOG_GAMMA -6.907755278982137f
#define TWO_PI    6.283185307179586

typedef __attribute__((ext_vector_type(8))) short bf16x8;
typedef __attribute__((ext_vector_type(4))) float f32x4;
typedef unsigned short u16;

__device__ __forceinline__ u16 f2bf(float x) {         // RNE float->bf16 bits
    unsigned u = __float_as_uint(x);
    unsigned r = (u + 0x7fffu + ((u >> 16) & 1u)) >> 16;
    return (u16)r;
}
__device__ __forceinline__ float bf2f(u16 b) {
    return __uint_as_float(((unsigned)b) << 16);
}

__device__ __forceinline__ void pf_sincos(float tau, int f, float* s, float* c) {
    // phase = exp(-2*pi*i * tau * f / T); reduce in double, eval in float
    double rev = (double)tau * (double)f * (1.0 / 1024.0);
    rev -= floor(rev);
    float ang = (float)(-TWO_PI * rev);
    __sincosf(ang, s, c);
}

// ---- per-row precompute: amp_src, tau_src, amp_rec, tau_rec, dec_prop, tau_prop
__global__ void k_per_row(const float* __restrict__ rpos,
                          const float* __restrict__ spos,
                          const float* __restrict__ cpos,
                          const float* __restrict__ avg_dist,
                          float* __restrict__ per_row) {
    int r = blockIdx.x * blockDim.x + threadIdx.x;
    if (r >= RR) return;
    float x = rpos[3*r], y = rpos[3*r+1], z = rpos[3*r+2];

    float dx = x - spos[0], dy = y - spos[1], dz = z - spos[2];
    float ds = sqrtf(dx*dx + dy*dy + dz*dz);
    per_row[0*RR + r] = (1.0f/(ds*ds + 0.001f)) * expf(KDECAY * ds);
    per_row[1*RR + r] = ds * (float)TAU_SCALE;

    dx = x - cpos[0]; dy = y - cpos[1]; dz = z - cpos[2];
    float dr = sqrtf(dx*dx + dy*dy + dz*dz);
    per_row[2*RR + r] = (1.0f/(dr*dr + 0.001f)) * expf(KDECAY * dr);
    per_row[3*RR + r] = dr * (float)TAU_SCALE;

    float da = avg_dist[r];
    per_row[4*RR + r] = expf(KDECAY * da);
    per_row[5*RR + r] = da * (float)TAU_SCALE;
}

// ---- K[p][d][e] = refl*sc*basis0[d][e] + refl*(1-sc)*basis1[d][e]
__global__ void k_build_K(const float* __restrict__ absorption,
                          const float* __restrict__ scattering,
                          const int* __restrict__ object_ids,
                          const float* __restrict__ basis,
                          float* __restrict__ Kmat) {
    int idx = blockIdx.x * 256 + threadIdx.x;   // p*16384 + d*128 + e
    int p  = idx >> 14;
    int de = idx & 16383;
    int obj = object_ids[p];
    float refl = 1.0f - absorption[obj];
    float sc   = scattering[obj];
    Kmat[idx] = refl*sc*basis[de] + refl*(1.0f - sc)*basis[16384 + de];
}

// ---- CSR build
__global__ void k_count(const int* __restrict__ gk_row, int* __restrict__ counts) {
    int e = blockIdx.x * 256 + threadIdx.x;
    atomicAdd(&counts[gk_row[e]], 1);
}

__global__ __launch_bounds__(1024) void k_scan(const int* __restrict__ counts,
                                               int* __restrict__ row_start,
                                               int* __restrict__ cursor) {
    __shared__ int sh[1024];
    int tid = threadIdx.x;
    int base = tid * 16;
    int local[16];
    int sum = 0;
    #pragma unroll
    for (int j = 0; j < 16; j++) { local[j] = sum; sum += counts[base + j]; }
    sh[tid] = sum;
    __syncthreads();
    for (int off = 1; off < 1024; off <<= 1) {
        int v = (tid >= off) ? sh[tid - off] : 0;
        __syncthreads();
        sh[tid] += v;
        __syncthreads();
    }
    int chunk_excl = sh[tid] - sum;   // exclusive prefix of this 16-chunk
    #pragma unroll
    for (int j = 0; j < 16; j++) {
        int v = chunk_excl + local[j];
        row_start[base + j] = v;
        cursor[base + j] = v;
    }
    if (tid == 1023) row_start[RR] = chunk_excl + sum;
}

// scatter packing {col, val} per edge -> one b64 load in segsum
__global__ void k_scatter(const int* __restrict__ gk_row,
                          const float* __restrict__ gk_val,
                          const int* __restrict__ gk_col,
                          int* __restrict__ cursor,
                          int2* __restrict__ edge) {
    int e = blockIdx.x * 256 + threadIdx.x;
    int pos = atomicAdd(&cursor[gk_row[e]], 1);
    edge[pos] = make_int2(gk_col[e], __float_as_int(gk_val[e]));
}

// ---- init: cur[r][f] = amp_src*phase(tau_src) (bf16); fused rad receiver-echo
__global__ __launch_bounds__(256) void k_init(const float* __restrict__ per_row,
                                              u16* __restrict__ cur,
                                              float* __restrict__ echo) {
    int fl = threadIdx.x & 63, rg = threadIdx.x >> 6;
    int f = blockIdx.x * 64 + fl;               // < 576
    float ar = 0.f, ai = 0.f;
    int r0 = blockIdx.y * 128;
    if (f < FP) {
        for (int k = rg; k < 128; k += 4) {
            int r = r0 + k;
            float amp = per_row[r], tau = per_row[RR + r];
            float s, c; pf_sincos(tau, f, &s, &c);
            float re = amp * c, im = amp * s;
            unsigned pk = (unsigned)f2bf(re) | ((unsigned)f2bf(im) << 16);
            *(unsigned*)(cur + (size_t)r * FP2 + f * 2) = pk;
            if (f < FF) {
                float w = per_row[2*RR + r], taur = per_row[3*RR + r];
                float s2, c2; pf_sincos(taur, f, &s2, &c2);
                ar = fmaf(w, c2*re - s2*im, ar);
                ai = fmaf(w, c2*im + s2*re, ai);
            }
        }
    }
    __shared__ float sh[4][64][2];
    sh[rg][fl][0] = ar; sh[rg][fl][1] = ai;
    __syncthreads();
    if (rg == 0 && f < FF) {
        float sx = sh[0][fl][0]+sh[1][fl][0]+sh[2][fl][0]+sh[3][fl][0];
        float sy = sh[0][fl][1]+sh[1][fl][1]+sh[2][fl][1]+sh[3][fl][1];
        atomicAdd(&echo[2*f],   sx);
        atomicAdd(&echo[2*f+1], sy);
    }
}

// ---- matmul + prop via MFMA, bf16 state planes.
// out[p] = K[p] (128x128 fp32, hi/lo split) x V[p] (128x1040 bf16 -> exact).
// Per kt: Ah*B + Al*B = 4 MFMAs (Bl term vanished: B is exactly bf16).
// Grid 512 = 128 p x 4 n-chunks (XCD-swizzled on p); block = 4 waves.
// V staged bf16->float into double-buffered LDS (VSTRIDE 18, conflict-free);
// fragment paths identical to verified R8 kernel.
__global__ __launch_bounds__(256) void k_matmul(const float* __restrict__ Kmat,
                                                const u16* __restrict__ in,
                                                const float* __restrict__ per_row,
                                                u16* __restrict__ out) {
    __shared__ float vlds[2][128 * VSTRIDE];
    int b = blockIdx.x;
    int xcd = b & 7;
    int g = b >> 3;                  // 0..63
    int p = (g >> 2) * 8 + xcd;
    int nq = g & 3;
    int nt0 = nq * 16;
    int ntEnd = (nq == 3) ? 65 : nt0 + 16;

    int tid  = threadIdx.x;
    int wave = tid >> 6;
    int lane = tid & 63;
    int quad = lane >> 4;
    int n    = lane & 15;
    int mt0  = wave << 1;

    // A fragments (hi/lo) for this wave's two M-tiles, all 4 K-tiles
    bf16x8 Ah[2][4], Al[2][4];
    #pragma unroll
    for (int mi = 0; mi < 2; mi++) {
        const float* kp = Kmat + (p << 14) + ((mt0 + mi) * 16 + n) * 128 + quad * 8;
        #pragma unroll
        for (int kt = 0; kt < 4; kt++) {
            float4 x0 = *(const float4*)(kp + kt * 32);
            float4 x1 = *(const float4*)(kp + kt * 32 + 4);
            float xs[8] = {x0.x,x0.y,x0.z,x0.w,x1.x,x1.y,x1.z,x1.w};
            bf16x8 h, l;
            #pragma unroll
            for (int j = 0; j < 8; j++) {
                u16 hb = f2bf(xs[j]);
                h[j] = (short)hb;
                l[j] = (short)f2bf(xs[j] - bf2f(hb));
            }
            Ah[mi][kt] = h; Al[mi][kt] = l;
        }
    }
    // per-output-row prop constants (row within tile = quad*4 + reg)
    float dec_[2][4], tau_[2][4];
    #pragma unroll
    for (int mi = 0; mi < 2; mi++)
        #pragma unroll
        for (int r = 0; r < 4; r++) {
            int row = (p << 7) + (mt0 + mi) * 16 + quad * 4 + r;
            dec_[mi][r] = per_row[4*RR + row];
            tau_[mi][r] = per_row[5*RR + row];
        }

    const u16* pin = in + (size_t)(p << 7) * FP2;
    uint4 pk;
    int se = tid >> 1, sc8 = (tid & 1) << 3;     // staging: e-row, 8-col group
    auto loadTile = [&](int nt) {
        pk = *(const uint4*)(pin + (size_t)se * FP2 + nt * 16 + sc8);
    };
    auto writeTile = [&](int buf) {
        float* dst = &vlds[buf][se * VSTRIDE + sc8];
        unsigned w[4] = {pk.x, pk.y, pk.z, pk.w};
        #pragma unroll
        for (int j = 0; j < 4; j++)
            *(float2*)(dst + 2*j) = make_float2(bf2f((u16)(w[j] & 0xffffu)),
                                                bf2f((u16)(w[j] >> 16)));
    };

    loadTile(nt0); writeTile(0);
    for (int nt = nt0; nt < ntEnd; nt++) {
        int cb = (nt - nt0) & 1;
        __syncthreads();                    // vlds[cb] ready for read
        if (nt + 1 < ntEnd) { loadTile(nt + 1); writeTile(cb ^ 1); }

        f32x4 acc0 = {0.f,0.f,0.f,0.f}, acc1 = {0.f,0.f,0.f,0.f};
        const float* vb = &vlds[cb][0];
        #pragma unroll
        for (int kt = 0; kt < 4; kt++) {
            bf16x8 Bh;
            #pragma unroll
            for (int j = 0; j < 8; j++) {
                float x = vb[(kt*32 + quad*8 + j) * VSTRIDE + n];
                Bh[j] = (short)f2bf(x);     // exact: x is a bf16 value
            }
            acc0 = __builtin_amdgcn_mfma_f32_16x16x32_bf16(Ah[0][kt], Bh, acc0, 0,0,0);
            acc1 = __builtin_amdgcn_mfma_f32_16x16x32_bf16(Ah[1][kt], Bh, acc1, 0,0,0);
            acc0 = __builtin_amdgcn_mfma_f32_16x16x32_bf16(Al[0][kt], Bh, acc0, 0,0,0);
            acc1 = __builtin_amdgcn_mfma_f32_16x16x32_bf16(Al[1][kt], Bh, acc1, 0,0,0);
        }

        // prop epilogue: complex rotate via re/im partner in adjacent lane
        int nfl = nt * 16 + n;              // bf16 index in row, < 1040
        int f   = nfl >> 1;
        bool odd = nfl & 1;
        #pragma unroll
        for (int mi = 0; mi < 2; mi++) {
            f32x4 a = mi ? acc1 : acc0;
            #pragma unroll
            for (int r = 0; r < 4; r++) {
                float av = a[r];
                float pv = __shfl_xor(av, 1);
                float s, c; pf_sincos(tau_[mi][r], f, &s, &c);
                float o = dec_[mi][r] * (odd ? fmaf(av, c,  s*pv)
                                             : fmaf(av, c, -s*pv));
                int row = (p << 7) + (mt0 + mi) * 16 + quad * 4 + r;
                out[(size_t)row * FP2 + nfl] = f2bf(o);
            }
        }
    }
}

// ---- segment sum + fused receiver-echo epilogue (bf16 planes).
// 4096 blocks x 512 thr = 128 fl x 4 ry. Per edge per lane: 4 dword gathers
// (re,im bf16 pairs at f=fl+128s) + tail (fl<8). fp32 accumulate; bf16 store.
__global__ __launch_bounds__(512) void k_segsum(const int* __restrict__ row_start,
                                                const int2* __restrict__ edge,
                                                const u16* __restrict__ in,
                                                u16* __restrict__ outp,
                                                const float* __restrict__ per_row,
                                                float2* __restrict__ part,
                                                int store_cur) {
    __shared__ float2 sh[4][128][5];
    int rb = blockIdx.x;
    int fl = threadIdx.x & 127, ry = threadIdx.x >> 7;
    int row = (rb << 2) + ry;
    int s0 = row_start[row], s1 = row_start[row + 1];
    float a0r=0.f,a0i=0.f,a1r=0.f,a1i=0.f,a2r=0.f,a2i=0.f,a3r=0.f,a3i=0.f;
    float t4r=0.f,t4i=0.f;
    bool tail = (fl < 8);
    for (int t = s0; t < s1; t++) {
        int2 ed = edge[t];
        float v = __int_as_float(ed.y);
        const u16* g = in + (size_t)ed.x * FP2 + (fl << 1);
        unsigned b0 = *(const unsigned*)(g);
        unsigned b1 = *(const unsigned*)(g + 256);
        unsigned b2 = *(const unsigned*)(g + 512);
        unsigned b3 = *(const unsigned*)(g + 768);
        a0r = fmaf(v, bf2f((u16)(b0 & 0xffffu)), a0r); a0i = fmaf(v, bf2f((u16)(b0 >> 16)), a0i);
        a1r = fmaf(v, bf2f((u16)(b1 & 0xffffu)), a1r); a1i = fmaf(v, bf2f((u16)(b1 >> 16)), a1i);
        a2r = fmaf(v, bf2f((u16)(b2 & 0xffffu)), a2r); a2i = fmaf(v, bf2f((u16)(b2 >> 16)), a2i);
        a3r = fmaf(v, bf2f((u16)(b3 & 0xffffu)), a3r); a3i = fmaf(v, bf2f((u16)(b3 >> 16)), a3i);
        if (tail) {
            unsigned b4 = *(const unsigned*)(g + 1024);
            t4r = fmaf(v, bf2f((u16)(b4 & 0xffffu)), t4r); t4i = fmaf(v, bf2f((u16)(b4 >> 16)), t4i);
        }
    }
    if (store_cur) {
        u16* w = outp + (size_t)row * FP2 + (fl << 1);
        *(unsigned*)(w)       = (unsigned)f2bf(a0r) | ((unsigned)f2bf(a0i) << 16);
        *(unsigned*)(w + 256) = (unsigned)f2bf(a1r) | ((unsigned)f2bf(a1i) << 16);
        *(unsigned*)(w + 512) = (unsigned)f2bf(a2r) | ((unsigned)f2bf(a2i) << 16);
        *(unsigned*)(w + 768) = (unsigned)f2bf(a3r) | ((unsigned)f2bf(a3i) << 16);
        if (tail)
            *(unsigned*)(w + 1024) = (unsigned)f2bf(t4r) | ((unsigned)f2bf(t4i) << 16);
    }
    // echo epilogue: contrib(f) = w_rec * phase(tau_rec, f) * value (fp32, pre-round)
    float wr = per_row[2*RR + row], taur = per_row[3*RR + row];
    {
        float s, c;
        pf_sincos(taur, fl, &s, &c);
        sh[ry][fl][0] = make_float2(wr*(c*a0r - s*a0i), wr*(c*a0i + s*a0r));
        pf_sincos(taur, fl + 128, &s, &c);
        sh[ry][fl][1] = make_float2(wr*(c*a1r - s*a1i), wr*(c*a1i + s*a1r));
        pf_sincos(taur, fl + 256, &s, &c);
        sh[ry][fl][2] = make_float2(wr*(c*a2r - s*a2i), wr*(c*a2i + s*a2r));
        pf_sincos(taur, fl + 384, &s, &c);
        sh[ry][fl][3] = make_float2(wr*(c*a3r - s*a3i), wr*(c*a3i + s*a3r));
        float2 c4 = make_float2(0.f, 0.f);
        if (tail && (512 + fl) < FF) {       // f=512 only
            pf_sincos(taur, 512 + fl, &s, &c);
            c4 = make_float2(wr*(c*t4r - s*t4i), wr*(c*t4i + s*t4r));
        }
        sh[ry][fl][4] = c4;
    }
    __syncthreads();
    if (ry == 0) {
        float2* pp = part + (size_t)rb * PSTRIDE;
        #pragma unroll
        for (int sidx = 0; sidx < 5; sidx++) {
            int fidx = sidx * 128 + fl;
            if (fidx < FP) {
                float2 v0 = sh[0][fl][sidx], v1 = sh[1][fl][sidx];
                float2 v2 = sh[2][fl][sidx], v3 = sh[3][fl][sidx];
                float2 acc = pp[fidx];
                acc.x += v0.x + v1.x + v2.x + v3.x;
                acc.y += v0.y + v1.y + v2.y + v3.y;
                pp[fidx] = acc;
            }
        }
    }
}

// ---- fold echo partials: echo[f] += sum_rb part[rb][f]
__global__ __launch_bounds__(256) void k_fold(const float2* __restrict__ part,
                                              float* __restrict__ echo) {
    int f = blockIdx.x;     // 0..FF-1
    float sx = 0.f, sy = 0.f;
    for (int rb = threadIdx.x; rb < NRB; rb += 256) {
        float2 v = part[(size_t)rb * PSTRIDE + f];
        sx += v.x; sy += v.y;
    }
    for (int off = 32; off >= 1; off >>= 1) {
        sx += __shfl_down(sx, off, 64);
        sy += __shfl_down(sy, off, 64);
    }
    __shared__ float red[2][4];
    int lane = threadIdx.x & 63, w = threadIdx.x >> 6;
    if (lane == 0) { red[0][w] = sx; red[1][w] = sy; }
    __syncthreads();
    if (threadIdx.x == 0) {
        sx = red[0][0]+red[0][1]+red[0][2]+red[0][3];
        sy = red[1][0]+red[1][1]+red[1][2]+red[1][3];
        echo[2*f] += sx;
        echo[2*f+1] += sy;
    }
}

// ---- irfft(n=1024) / fsm_window
__global__ void k_irfft(const float* __restrict__ echo, float* __restrict__ out) {
    int t = blockIdx.x * blockDim.x + threadIdx.x;   // 0..1023
    float acc = echo[0];                              // f=0 (real)
    float nyq = echo[2 * 512];                        // Nyquist real part
    acc += (t & 1) ? -nyq : nyq;
    for (int f = 1; f < 512; f++) {
        int m = (f * t) & 1023;
        float ang = (float)m * 0.006135923151542565f;  // 2*pi/1024
        float s, c; __sincosf(ang, &s, &c);
        acc += 2.0f * (echo[2*f]*c - echo[2*f+1]*s);
    }
    acc *= (1.0f / 1024.0f);
    float tsec = (float)t * (1.0f / 16000.0f);
    float win = expf(LOG_GAMMA * tsec);
    out[t] = acc / win;
}

extern "C" void kernel_launch(void* const* d_in, const int* in_sizes, int n_in,
                              void* d_out, int out_size, void* d_ws, size_t ws_size,
                              hipStream_t stream) {
    const float* source_pos   = (const float*)d_in[0];
    const float* receiver_pos = (const float*)d_in[1];
    const float* absorption   = (const float*)d_in[2];
    const float* scattering   = (const float*)d_in[3];
    const float* gk_val       = (const float*)d_in[4];
    const float* basis        = (const float*)d_in[5];
    const float* avg_dist     = (const float*)d_in[6];
    const float* rpos         = (const float*)d_in[7];
    const int*   gk_row       = (const int*)d_in[8];
    const int*   gk_col       = (const int*)d_in[9];
    const int*   object_ids   = (const int*)d_in[10];
    float* out = (float*)d_out;

    char* base = (char*)d_ws;
    size_t off = 0;
    auto alloc = [&](size_t bytes) -> void* {
        void* ptr = base + off;
        off = (off + bytes + 255) & ~(size_t)255;
        return ptr;
    };
    const size_t PLANE = (size_t)RR * FP2 + FP2;   // +1 row slack (bf16 elems)
    float*  Kmat      = (float*)alloc(sizeof(float) * PP * DD * DD);
    u16*    cur       = (u16*)alloc(sizeof(u16) * PLANE);
    u16*    nxt       = (u16*)alloc(sizeof(u16) * PLANE);
    float*  per_row   = (float*)alloc(sizeof(float) * 6 * RR);
    int*    counts    = (int*)alloc(sizeof(int) * RR);
    int*    row_start = (int*)alloc(sizeof(int) * (RR + 1));
    int*    cursor    = (int*)alloc(sizeof(int) * RR);
    int2*   edge      = (int2*)alloc(sizeof(int2) * EE);
    float2* part      = (float2*)alloc(sizeof(float2) * NRB * PSTRIDE);
    float*  echo      = (float*)alloc(sizeof(float) * 1056);

    hipMemsetAsync(counts, 0, sizeof(int) * RR, stream);
    hipMemsetAsync(echo, 0, sizeof(float) * 1056, stream);
    hipMemsetAsync(part, 0, sizeof(float2) * NRB * PSTRIDE, stream);

    k_per_row<<<RR / 256, 256, 0, stream>>>(rpos, source_pos, receiver_pos, avg_dist, per_row);
    k_build_K<<<(PP * DD * DD) / 256, 256, 0, stream>>>(absorption, scattering, object_ids, basis, Kmat);
    k_count<<<EE / 256, 256, 0, stream>>>(gk_row, counts);
    k_scan<<<1, 1024, 0, stream>>>(counts, row_start, cursor);
    k_scatter<<<EE / 256, 256, 0, stream>>>(gk_row, gk_val, gk_col, cursor, edge);
    k_init<<<dim3(9, 128), 256, 0, stream>>>(per_row, cur, echo);

    for (int b = 0; b < 4; b++) {
        k_matmul<<<512, 256, 0, stream>>>(Kmat, cur, per_row, nxt);
        k_segsum<<<NRB, 512, 0, stream>>>(row_start, edge, nxt, cur,
                                          per_row, part, (b < 3) ? 1 : 0);
    }

    k_fold<<<FF, 256, 0, stream>>>(part, echo);
    k_irfft<<<4, 256, 0, stream>>>(echo, out);
}